// Round 13
// baseline (2607.386 us; speedup 1.0000x reference)
//
#include <hip/hip_runtime.h>

typedef _Float16 v8h __attribute__((ext_vector_type(8)));
typedef float v4f __attribute__((ext_vector_type(4)));

#define NT 1024
#define XSTR 344   // x row stride (halves)
#define HSTR 1032  // h row stride (halves)

// ws layout (halves), sites are [1024 tid][8]:
//  W1H [site s=a*20+p*2+u, 0..39]  at 0       (327680)   16 KB/site
//  W1L                             at 327680
//  W2H [site q, 0..31]             at 655360  (262144)
//  W2L                             at 917504
//  att (transposed actions, float) at byte 2359296
static constexpr size_t ATT_BYTES_NEEDED = 2359296ull + 4096ull * 64 * 64 * 4;

#define MFMA16 __builtin_amdgcn_mfma_f32_16x16x32_f16

#define GLOAD(dst, base, vo) \
  asm volatile("global_load_dwordx4 %0, %1, %2" : "=v"(dst) : "v"(vo), "s"(base))
#define VMW_(n) asm volatile("s_waitcnt vmcnt(" #n ")" ::: "memory")
#define VMW(n) do { VMW_(n); __builtin_amdgcn_sched_barrier(0); } while (0)
#define LGKMBAR() do { asm volatile("s_waitcnt lgkmcnt(0)" ::: "memory"); \
  __builtin_amdgcn_s_barrier(); } while (0)

__device__ __forceinline__ float tanh_fast(float a) {
  float e = __expf(2.0f * a);
  return 1.0f - __fdividef(2.0f, e + 1.0f);
}

extern "C" __global__ void conv_w(const float* __restrict__ W1,
                                  const float* __restrict__ W2,
                                  _Float16* __restrict__ ws) {
  int i = blockIdx.x * 256 + threadIdx.x;        // 917504 total
  if (i < 327680) {
    int jj = i & 7, tid = (i >> 3) & 1023, s = i >> 13;
    int w = tid >> 6, g = (tid >> 4) & 3, l15 = tid & 15;
    int a = s / 20, r = s % 20, p = r >> 1, u = r & 1;
    int col = (a * 2 + u) * 256 + w * 16 + l15;
    float v = W1[(p * 32 + g * 8 + jj) * 1024 + col];
    _Float16 hh = (_Float16)v;
    ws[i] = hh;
    ws[327680 + i] = (_Float16)((v - (float)hh) * 2048.f);
  } else {
    int iq = i - 655360;
    if (iq >= 0) {
      int jj = iq & 7, tid = (iq >> 3) & 1023, q = iq >> 13;
      int w = tid >> 6, g = (tid >> 4) & 3, l15 = tid & 15;
      float v = W2[(q * 32 + g * 8 + jj) * 256 + w * 16 + l15];
      _Float16 hh = (_Float16)v;
      ws[655360 + iq] = hh;
      ws[917504 + iq] = (_Float16)((v - (float)hh) * 2048.f);
    }
  }
}

extern "C" __global__ void conv_a(const float* __restrict__ actions,
                                  float* __restrict__ att) {
  size_t o = (size_t)blockIdx.x * 256 + threadIdx.x;
  int f = (int)(o & 63);
  int b = (int)((o >> 6) & 4095);
  int t = (int)(o >> 18);
  att[o] = actions[((size_t)b * 64 + f) * 64 + t];
}

// G1 body p (literal 0..9): consume slots p&1 (2 col-tiles u=0,1), refill
// sites for body p+2 via vo1 if RF; x parity ring, PF0 reloads frag 0 at p==9
#define G1BODY(p, RF, N, PF0) do { \
    VMW(N); \
    v8h bh0 = B1H0[(p) & 1], bl0 = B1L0[(p) & 1]; \
    v8h bh1 = B1H1[(p) & 1], bl1 = B1L1[(p) & 1]; \
    if (RF) { \
      GLOAD(B1H0[(p) & 1], w1hB, vo1); GLOAD(B1L0[(p) & 1], w1lB, vo1); \
      GLOAD(B1H1[(p) & 1], w1hB, vo1 + 16384); \
      GLOAD(B1L1[(p) & 1], w1lB, vo1 + 16384); \
      vo1 += 32768; } \
    v8h xch = Xh[(p) & 1], xcl = Xl[(p) & 1]; \
    if ((p) < 9) { \
      Xh[((p) + 1) & 1] = *(const v8h*)&xHs[xbase + ((p) + 1) * 32]; \
      Xl[((p) + 1) & 1] = *(const v8h*)&xLs[xbase + ((p) + 1) * 32]; \
    } else if (PF0) { \
      Xh[0] = *(const v8h*)&xHs[xbase]; \
      Xl[0] = *(const v8h*)&xLs[xbase]; \
    } \
    acc0H = MFMA16(xch, bh0, acc0H, 0, 0, 0); \
    acc0M = MFMA16(xch, bl0, acc0M, 0, 0, 0); \
    acc0M = MFMA16(xcl, bh0, acc0M, 0, 0, 0); \
    acc1H = MFMA16(xch, bh1, acc1H, 0, 0, 0); \
    acc1M = MFMA16(xch, bl1, acc1M, 0, 0, 0); \
    acc1M = MFMA16(xcl, bh1, acc1M, 0, 0, 0); \
  } while (0)

// load one (slot, site-pair) of the B1 ring
#define B1PRO(sl, s0) do { \
    GLOAD(B1H0[sl], w1hB, tid16 + (s0) * 16384); \
    GLOAD(B1L0[sl], w1lB, tid16 + (s0) * 16384); \
    GLOAD(B1H1[sl], w1hB, tid16 + ((s0) + 1) * 16384); \
    GLOAD(B1L1[sl], w1lB, tid16 + ((s0) + 1) * 16384); \
  } while (0)

// B2 prologue: sites 0,1,2 -> ring slots 0,1,2
#define B2PRO3() do { \
    GLOAD(B2H[0], w2hB, tid16);          GLOAD(B2L[0], w2lB, tid16); \
    GLOAD(B2H[1], w2hB, tid16 + 16384);  GLOAD(B2L[1], w2lB, tid16 + 16384); \
    GLOAD(B2H[2], w2hB, tid16 + 32768);  GLOAD(B2L[2], w2lB, tid16 + 32768); \
  } while (0)

// G2 body: s3 = q%3 literal, par = q&1 literal; refill site q+3 if RF;
// RD: prefetch h frag q+1 at hbase+nxt
#define G2BODY(s3, par, RF, RD, N, nxt) do { \
    VMW(N); \
    v8h bh = B2H[s3], bl = B2L[s3]; \
    if (RF) { GLOAD(B2H[s3], w2hB, vo2); GLOAD(B2L[s3], w2lB, vo2); \
              vo2 += 16384; } \
    v8h hch = Hh[par], hcl = Hl_[par]; \
    if (RD) { \
      Hh[(par) ^ 1]  = *(const v8h*)&hHs[hbase + (nxt)]; \
      Hl_[(par) ^ 1] = *(const v8h*)&hLs[hbase + (nxt)]; } \
    cH = MFMA16(hch, bh, cH, 0, 0, 0); \
    cM = MFMA16(hch, bl, cM, 0, 0, 0); \
    cM = MFMA16(hcl, bh, cM, 0, 0, 0); \
  } while (0)

extern "C" __global__ void __launch_bounds__(NT)
ode_kernel(const float* __restrict__ actions, const float* __restrict__ att,
           const float* __restrict__ y0,
           const float* __restrict__ b1f, const float* __restrict__ b2f,
           const float* __restrict__ dtp, const _Float16* __restrict__ ws,
           float* __restrict__ out)
{
  __shared__ __align__(16) _Float16 xHs[16 * XSTR], xLs[16 * XSTR];
  __shared__ __align__(16) _Float16 hHs[16 * HSTR], hLs[16 * HSTR];

  const int tid  = threadIdx.x;
  const int lane = tid & 63;
  const int l15  = lane & 15, g = lane >> 4;
  const int w    = tid >> 6;                 // wave 0..15
  const int nl   = w * 16 + l15;             // this thread's G2 output col
  const int b0   = blockIdx.x * 16;
  const float dt = dtp[0];
  const int tid16 = tid * 16;

  const _Float16* w1hB = ws;
  const _Float16* w1lB = ws + 327680;
  const _Float16* w2hB = ws + 655360;
  const _Float16* w2lB = ws + 917504;

  // biases in registers
  float b1r[4];
  #pragma unroll
  for (int j = 0; j < 4; ++j) b1r[j] = b1f[j * 256 + nl];
  const float b2r = b2f[nl];

  // y state: rows g*4+r, col nl
  float ya[4];
  #pragma unroll
  for (int r = 0; r < 4; ++r) {
    ya[r] = y0[(size_t)(b0 + g * 4 + r) * 256 + nl];
    out[((size_t)((b0 + g * 4 + r) * 256 + nl)) * 64] = ya[r];
  }

  const int xbase = l15 * XSTR + g * 8;
  const int hbase = l15 * HSTR + g * 8;

  v8h B1H0[2], B1L0[2], B1H1[2], B1L1[2];   // pinned: 8 quads
  v8h B2H[3], B2L[3];                       // pinned: 6 quads
  v8h Xh[2], Xl[2], Hh[2], Hl_[2];

  // initial G1 prologue: sites 0..3 (pass A bodies 0,1)
  B1PRO(0, 0); B1PRO(1, 2);

  #pragma unroll 1
  for (int t = 0; t < 63; ++t) {
    // ---- x-phase: x = [a_t | y] hi/lo planes
    {
      int m = tid >> 6, k = tid & 63;
      float v = att ? att[((size_t)t * 4096 + b0 + m) * 64 + k]
                    : actions[((size_t)(b0 + m) * 64 + k) * 64 + t];
      _Float16 hh = (_Float16)v;
      xHs[m * XSTR + k] = hh;
      xLs[m * XSTR + k] = (_Float16)((v - (float)hh) * 2048.f);
    }
    #pragma unroll
    for (int r = 0; r < 4; ++r) {
      int m = g * 4 + r;
      _Float16 h0 = (_Float16)ya[r];
      xHs[m * XSTR + 64 + nl] = h0;
      xLs[m * XSTR + 64 + nl] = (_Float16)((ya[r] - (float)h0) * 2048.f);
    }
    LGKMBAR();   // x visible; B1 prologue loads stay in flight

    Xh[0] = *(const v8h*)&xHs[xbase];
    Xl[0] = *(const v8h*)&xLs[xbase];

    // ======== GEMM1 pass A (cols 0..511): 10 bodies, refill +2 ========
    int vo1 = tid16 + 4 * 16384;   // refills: sites 4..19
    {
      v4f acc0H = v4f{b1r[0], b1r[0], b1r[0], b1r[0]};
      v4f acc1H = v4f{b1r[1], b1r[1], b1r[1], b1r[1]};
      v4f acc0M = v4f{0.f, 0.f, 0.f, 0.f}, acc1M = acc0M;
      G1BODY(0, 1, 4, 0); G1BODY(1, 1, 4, 0); G1BODY(2, 1, 4, 0);
      G1BODY(3, 1, 4, 0); G1BODY(4, 1, 4, 0); G1BODY(5, 1, 4, 0);
      G1BODY(6, 1, 4, 0); G1BODY(7, 1, 4, 0);
      G1BODY(8, 0, 4, 0); B1PRO(0, 20);    // pass B bodies 0 sites
      G1BODY(9, 0, 4, 1); B1PRO(1, 22);    // pass B body 1 sites
      #pragma unroll
      for (int r = 0; r < 4; ++r) {
        int m = g * 4 + r;
        float v0 = acc0H[r] + acc0M[r] * (1.f / 2048.f);
        float t0 = tanh_fast(v0);
        _Float16 e0 = (_Float16)t0;
        hHs[m * HSTR + nl] = e0;
        hLs[m * HSTR + nl] = (_Float16)((t0 - (float)e0) * 2048.f);
        float v1 = acc1H[r] + acc1M[r] * (1.f / 2048.f);
        float t1 = tanh_fast(v1);
        _Float16 e1 = (_Float16)t1;
        hHs[m * HSTR + 256 + nl] = e1;
        hLs[m * HSTR + 256 + nl] = (_Float16)((t1 - (float)e1) * 2048.f);
      }
    }
    // ======== GEMM1 pass B (cols 512..1023): 10 bodies, refill +2 ========
    vo1 = tid16 + 24 * 16384;   // refills: sites 24..39
    {
      v4f acc0H = v4f{b1r[2], b1r[2], b1r[2], b1r[2]};
      v4f acc1H = v4f{b1r[3], b1r[3], b1r[3], b1r[3]};
      v4f acc0M = v4f{0.f, 0.f, 0.f, 0.f}, acc1M = acc0M;
      G1BODY(0, 1, 4, 0); G1BODY(1, 1, 4, 0); G1BODY(2, 1, 4, 0);
      G1BODY(3, 1, 4, 0); G1BODY(4, 1, 4, 0); G1BODY(5, 1, 4, 0);
      G1BODY(6, 1, 4, 0); G1BODY(7, 1, 4, 0);
      G1BODY(8, 0, 4, 0);
      G1BODY(9, 0, 0, 0);
      B2PRO3();                              // 6 loads in flight across barrier
      #pragma unroll
      for (int r = 0; r < 4; ++r) {
        int m = g * 4 + r;
        float v0 = acc0H[r] + acc0M[r] * (1.f / 2048.f);
        float t0 = tanh_fast(v0);
        _Float16 e0 = (_Float16)t0;
        hHs[m * HSTR + 512 + nl] = e0;
        hLs[m * HSTR + 512 + nl] = (_Float16)((t0 - (float)e0) * 2048.f);
        float v1 = acc1H[r] + acc1M[r] * (1.f / 2048.f);
        float t1 = tanh_fast(v1);
        _Float16 e1 = (_Float16)t1;
        hHs[m * HSTR + 768 + nl] = e1;
        hLs[m * HSTR + 768 + nl] = (_Float16)((t1 - (float)e1) * 2048.f);
      }
    }
    LGKMBAR();   // h visible; B2 sites 0..2 stay in flight

    Hh[0]  = *(const v8h*)&hHs[hbase];
    Hl_[0] = *(const v8h*)&hLs[hbase];

    int vo2 = tid16 + 3 * 16384;   // refills: sites 3..31

    v4f cH = v4f{b2r, b2r, b2r, b2r};
    v4f cM = v4f{0.f, 0.f, 0.f, 0.f};

    // ======== GEMM2: 4 groups of 6 (q=0..23), then explicit q=24..31 ======
    #pragma unroll 1
    for (int jj = 0; jj < 4; ++jj) {
      const int jb = jj * 192;
      G2BODY(0, 0, 1, 1, 4, jb + 32);
      G2BODY(1, 1, 1, 1, 4, jb + 64);
      G2BODY(2, 0, 1, 1, 4, jb + 96);
      G2BODY(0, 1, 1, 1, 4, jb + 128);
      G2BODY(1, 0, 1, 1, 4, jb + 160);
      G2BODY(2, 1, 1, 1, 4, jb + 192);
    }
    G2BODY(0, 0, 1, 1, 4, 800);   // q=24
    G2BODY(1, 1, 1, 1, 4, 832);   // q=25
    G2BODY(2, 0, 1, 1, 4, 864);   // q=26
    G2BODY(0, 1, 1, 1, 4, 896);   // q=27
    G2BODY(1, 0, 1, 1, 4, 928);   // q=28 (refills site 31)
    G2BODY(2, 1, 0, 1, 4, 960);   // q=29
    G2BODY(0, 0, 0, 1, 2, 992);   // q=30
    G2BODY(1, 1, 0, 0, 0, 0);     // q=31

    // ---- y epilogue + out stores
    #pragma unroll
    for (int r = 0; r < 4; ++r) {
      float yn = ya[r] + dt * (cH[r] + cM[r] * (1.f / 2048.f));
      ya[r] = yn;
      out[((size_t)((b0 + g * 4 + r) * 256 + nl)) * 64 + (t + 1)] = yn;
    }
    // ---- next step's G1 pass-A prologue (sites 0..3)
    if (t < 62) { B1PRO(0, 0); B1PRO(1, 2); }
  }
}

extern "C" void kernel_launch(void* const* d_in, const int* in_sizes, int n_in,
                              void* d_out, int out_size, void* d_ws, size_t ws_size,
                              hipStream_t stream) {
  const float* actions = (const float*)d_in[1];
  const float* y0      = (const float*)d_in[2];
  const float* W1      = (const float*)d_in[3];
  const float* b1      = (const float*)d_in[4];
  const float* W2      = (const float*)d_in[5];
  const float* b2      = (const float*)d_in[6];
  const float* dtp     = (const float*)d_in[7];
  float* out = (float*)d_out;
  _Float16* ws = (_Float16*)d_ws;

  const bool use_att = ws_size >= ATT_BYTES_NEEDED;
  float* att = use_att ? (float*)((char*)d_ws + 2359296) : nullptr;

  hipLaunchKernelGGL(conv_w, dim3(3584), dim3(256), 0, stream, W1, W2, ws);
  if (use_att)
    hipLaunchKernelGGL(conv_a, dim3(65536), dim3(256), 0, stream, actions, att);
  hipLaunchKernelGGL(ode_kernel, dim3(256), dim3(NT), 0, stream,
                     actions, att, y0, b1, b2, dtp, ws, out);
}

// Round 14
// 2266.079 us; speedup vs baseline: 1.1506x; 1.1506x over previous
//
#include <hip/hip_runtime.h>

typedef _Float16 v8h __attribute__((ext_vector_type(8)));
typedef float v4f __attribute__((ext_vector_type(4)));

#define NT 512
#define XSTR 344   // x row stride (halves)
#define HSTR 1032  // h row stride (halves)

// ws layout (halves):
//  W1H [site gp=ph*10+p, 0..79][512 tid][8]  at 0        (327680)
//  W1L                                       at 327680
//  W2H [site s=p*2+ph2, 0..63][512 tid][8]   at 655360   (262144)
//  W2L                                       at 917504   (total 1179648 = 2.25 MB)
//  att (transposed actions, float)           at byte 2359296
static constexpr size_t ATT_BYTES_NEEDED = 2359296ull + 4096ull * 64 * 64 * 4;

#define MFMA16 __builtin_amdgcn_mfma_f32_16x16x32_f16

// pinned async load: compiler cannot sink/spill; completion via hand vmcnt
#define GLOAD(dst, base, vo) \
  asm volatile("global_load_dwordx4 %0, %1, %2" : "=v"(dst) : "v"(vo), "s"(base))
#define VMW_(n) asm volatile("s_waitcnt vmcnt(" #n ")" ::: "memory")
#define VMW(n) do { VMW_(n); __builtin_amdgcn_sched_barrier(0); } while (0)
#define LGKMBAR() do { asm volatile("s_waitcnt lgkmcnt(0)" ::: "memory"); \
  __builtin_amdgcn_s_barrier(); } while (0)

__device__ __forceinline__ float tanh_fast(float a) {
  float e = __expf(2.0f * a);
  return 1.0f - __fdividef(2.0f, e + 1.0f);
}

extern "C" __global__ void conv_w(const float* __restrict__ W1,
                                  const float* __restrict__ W2,
                                  _Float16* __restrict__ ws) {
  int i = blockIdx.x * 256 + threadIdx.x;        // 917504 total
  if (i < 327680) {
    int j = i & 7, lane = (i >> 3) & 63, w = (i >> 9) & 7, gp = i >> 12;
    int g = lane >> 4, l15 = lane & 15;
    int ph = gp / 10, p = gp % 10;
    float v = W1[(p * 32 + g * 8 + j) * 1024 + ph * 128 + w * 16 + l15];
    _Float16 hh = (_Float16)v;
    ws[i] = hh;
    ws[327680 + i] = (_Float16)((v - (float)hh) * 2048.f);
  } else {
    int iq = i - 655360;
    if (iq >= 0) {
      int j = iq & 7, t = (iq >> 3) & 511, s = iq >> 12;
      int lane = t & 63, wave = t >> 6, g = lane >> 4, l15 = lane & 15;
      int p = s >> 1, ph2 = s & 1;
      float v = W2[(p * 32 + g * 8 + j) * 256 + ph2 * 128 + wave * 16 + l15];
      _Float16 hh = (_Float16)v;
      ws[655360 + iq] = hh;
      ws[917504 + iq] = (_Float16)((v - (float)hh) * 2048.f);
    }
  }
}

extern "C" __global__ void conv_a(const float* __restrict__ actions,
                                  float* __restrict__ att) {
  size_t o = (size_t)blockIdx.x * 256 + threadIdx.x;
  int f = (int)(o & 63);
  int b = (int)((o >> 6) & 4095);
  int t = (int)(o >> 18);
  att[o] = actions[((size_t)b * 64 + f) * 64 + t];
}

// G1 body p: wait N, consume B slot p%5, refill next site (wrap at 80) if RF,
// x parity ring (reads frag 0 for next ph when p==9 && RD0)
#define G1BODY(p, RF, N, RD0) do { \
    VMW(N); \
    v8h bh = B1H[(p) % 5], bl = B1L[(p) % 5]; \
    if (RF) { GLOAD(B1H[(p) % 5], w1hB, vo1); GLOAD(B1L[(p) % 5], w1lB, vo1); \
              vo1 += 8192; if (vo1 == vend1) vo1 = tid16; } \
    v8h xch = Xh[(p) & 1], xcl = Xl[(p) & 1]; \
    if ((p) < 9) { \
      Xh[((p) + 1) & 1] = *(const v8h*)&xHs[xbase + ((p) + 1) * 32]; \
      Xl[((p) + 1) & 1] = *(const v8h*)&xLs[xbase + ((p) + 1) * 32]; \
    } else if (RD0) { \
      Xh[0] = *(const v8h*)&xHs[xbase]; \
      Xl[0] = *(const v8h*)&xLs[xbase]; \
    } \
    accH = MFMA16(xch, bh, accH, 0, 0, 0); \
    accM = MFMA16(xch, bl, accM, 0, 0, 0); \
    accM = MFMA16(xcl, bh, accM, 0, 0, 0); \
  } while (0)

// B2 prologue: chunk at byte offset off (runtime) into ring slot k (literal)
#define B2PRO(k, off) do { \
    GLOAD(B2H0[k], w2hB, (off)); \
    GLOAD(B2L0[k], w2lB, (off)); \
    GLOAD(B2H1[k], w2hB, (off) + 8192); \
    GLOAD(B2L1[k], w2lB, (off) + 8192); \
  } while (0)

// G2 body j: slot s3 (literal), parity par (literal); refill +3 (wrap 32 chunks);
// RD: read next h frag at hbase+hnx, advance hnx with &1023 wrap
#define G2BODY(j, s3, par, RF, RD, N) do { \
    VMW(N); \
    v8h bh0 = B2H0[s3], bl0 = B2L0[s3]; \
    v8h bh1 = B2H1[s3], bl1 = B2L1[s3]; \
    if (RF) { \
      GLOAD(B2H0[s3], w2hB, vo2); GLOAD(B2L0[s3], w2lB, vo2); \
      GLOAD(B2H1[s3], w2hB, vo2 + 8192); GLOAD(B2L1[s3], w2lB, vo2 + 8192); \
      vo2 += 16384; if (vo2 == vend2) vo2 = tid16; \
    } \
    v8h hch = Hh[par], hcl = Hl_[par]; \
    if (RD) { \
      Hh[(par) ^ 1]  = *(const v8h*)&hHs[hbase + hnx]; \
      Hl_[(par) ^ 1] = *(const v8h*)&hLs[hbase + hnx]; \
      hnx = (hnx + 32) & 1023; \
    } \
    c0H = MFMA16(hch, bh0, c0H, 0, 0, 0); \
    c0M = MFMA16(hch, bl0, c0M, 0, 0, 0); \
    c0M = MFMA16(hcl, bh0, c0M, 0, 0, 0); \
    c1H = MFMA16(hch, bh1, c1H, 0, 0, 0); \
    c1M = MFMA16(hch, bl1, c1M, 0, 0, 0); \
    c1M = MFMA16(hcl, bh1, c1M, 0, 0, 0); \
  } while (0)

extern "C" __global__ void __launch_bounds__(NT, 2)
ode_kernel(const float* __restrict__ actions, const float* __restrict__ att,
           const float* __restrict__ y0,
           const float* __restrict__ b1f, const float* __restrict__ b2f,
           const float* __restrict__ dtp, const _Float16* __restrict__ ws,
           float* __restrict__ out)
{
  __shared__ __align__(16) _Float16 xHs[16 * XSTR], xLs[16 * XSTR];
  __shared__ __align__(16) _Float16 hHs[16 * HSTR], hLs[16 * HSTR];
  __shared__ float b1s[1024];

  const int tid  = threadIdx.x;
  const int lane = tid & 63;
  const int l15  = lane & 15, g = lane >> 4;
  const int nloc = (tid >> 6) * 16 + l15;
  const int b0   = blockIdx.x * 16;
  const float dt = dtp[0];
  const int tid16 = tid * 16;

  // per-block walk rotation (varies within an XCD: XCD = blockIdx % 8)
  const int rot8  = (blockIdx.x >> 3) & 7;    // G1: start ph
  const int rot2c = (blockIdx.x >> 3) & 31;   // G2: start k-chunk
  const int vend1 = tid16 + 655360;           // 80 sites * 8192
  const int vend2 = tid16 + 524288;           // 32 chunks * 16384

  const _Float16* w1hB = ws;
  const _Float16* w1lB = ws + 327680;
  const _Float16* w2hB = ws + 655360;
  const _Float16* w2lB = ws + 917504;

  for (int i = tid; i < 1024; i += NT) b1s[i] = b1f[i];
  const float b2r0 = b2f[nloc], b2r1 = b2f[128 + nloc];

  float ya[4], yb[4];
  #pragma unroll
  for (int j = 0; j < 4; ++j) {
    int m = g * 4 + j;
    ya[j] = y0[(size_t)(b0 + m) * 256 + nloc];
    yb[j] = y0[(size_t)(b0 + m) * 256 + 128 + nloc];
    out[((size_t)((b0 + m) * 256 + nloc)) * 64] = ya[j];
    out[((size_t)((b0 + m) * 256 + 128 + nloc)) * 64] = yb[j];
  }

  const int xbase = l15 * XSTR + g * 8;
  const int hbase = l15 * HSTR + g * 8;

  v8h B1H[5], B1L[5];                       // pinned: 10 quads (R8)
  v8h B2H0[3], B2L0[3], B2H1[3], B2L1[3];   // pinned: 12 quads (R8)
  v8h Xh[2], Xl[2], Hh[2], Hl_[2];

  const int g1p0 = tid16 + rot8 * 81920;    // prologue base: site rot8*10

  // initial G1 prologue: sites rot8*10 .. +4
  #pragma unroll
  for (int s = 0; s < 5; ++s) {
    GLOAD(B1H[s], w1hB, g1p0 + s * 8192);
    GLOAD(B1L[s], w1lB, g1p0 + s * 8192);
  }

  #pragma unroll 1
  for (int t = 0; t < 63; ++t) {
    // ---- x-phase: x = [a_t | y] hi/lo planes
    #pragma unroll
    for (int it = 0; it < 2; ++it) {
      int o = tid + NT * it;
      int m = o >> 6, k = o & 63;
      float v = att ? att[((size_t)t * 4096 + b0 + m) * 64 + k]
                    : actions[((size_t)(b0 + m) * 64 + k) * 64 + t];
      _Float16 hh = (_Float16)v;
      xHs[m * XSTR + k] = hh;
      xLs[m * XSTR + k] = (_Float16)((v - (float)hh) * 2048.f);
    }
    #pragma unroll
    for (int j = 0; j < 4; ++j) {
      int m = g * 4 + j;
      _Float16 h0 = (_Float16)ya[j];
      xHs[m * XSTR + 64 + nloc] = h0;
      xLs[m * XSTR + 64 + nloc] = (_Float16)((ya[j] - (float)h0) * 2048.f);
      _Float16 h1 = (_Float16)yb[j];
      xHs[m * XSTR + 192 + nloc] = h1;
      xLs[m * XSTR + 192 + nloc] = (_Float16)((yb[j] - (float)h1) * 2048.f);
    }
    LGKMBAR();   // x visible; weight loads stay in flight

    // preload x frag 0
    Xh[0] = *(const v8h*)&xHs[xbase];
    Xl[0] = *(const v8h*)&xLs[xbase];

    int vo1 = g1p0 + 5 * 8192;   // next refill site = rot8*10+5 (<= 75, no wrap)

    // ======== GEMM1 rotated ph walk: iterations 0..6 uniform ========
    #pragma unroll 1
    for (int ph = 0; ph < 7; ++ph) {
      const int pha = (ph + rot8) & 7;          // actual ph this iteration
      const float bb = b1s[pha * 128 + nloc];
      v4f accH = v4f{bb, bb, bb, bb};
      v4f accM = v4f{0.f, 0.f, 0.f, 0.f};
      #pragma unroll
      for (int p = 0; p < 10; ++p) G1BODY(p, 1, 8, 1);
      #pragma unroll
      for (int j = 0; j < 4; ++j) {
        float v = accH[j] + accM[j] * (1.f / 2048.f);
        float th = tanh_fast(v);
        _Float16 hh = (_Float16)th;
        int m = g * 4 + j;
        hHs[m * HSTR + pha * 128 + nloc] = hh;
        hLs[m * HSTR + pha * 128 + nloc] = (_Float16)((th - (float)hh) * 2048.f);
      }
    }
    // ======== GEMM1 iteration 7: last 5 refills; B2 prologue @ bodies 6..8 ==
    {
      const int pha = (7 + rot8) & 7;
      const float bb = b1s[pha * 128 + nloc];
      v4f accH = v4f{bb, bb, bb, bb};
      v4f accM = v4f{0.f, 0.f, 0.f, 0.f};
      #pragma unroll
      for (int p = 0; p < 6; ++p) G1BODY(p, (p) < 5, 8, 1);
      G1BODY(6, 0, 6, 1);
      B2PRO(0, tid16 + ((rot2c + 0) & 31) * 16384);
      G1BODY(7, 0, 8, 1);
      B2PRO(1, tid16 + ((rot2c + 1) & 31) * 16384);
      G1BODY(8, 0, 10, 1);
      B2PRO(2, tid16 + ((rot2c + 2) & 31) * 16384);
      G1BODY(9, 0, 12, 0);
      #pragma unroll
      for (int j = 0; j < 4; ++j) {
        float v = accH[j] + accM[j] * (1.f / 2048.f);
        float th = tanh_fast(v);
        _Float16 hh = (_Float16)th;
        int m = g * 4 + j;
        hHs[m * HSTR + pha * 128 + nloc] = hh;
        hLs[m * HSTR + pha * 128 + nloc] = (_Float16)((th - (float)hh) * 2048.f);
      }
    }
    LGKMBAR();   // h visible; B2 chunks rot2c..rot2c+2 stay in flight

    // preload h frag rot2c; hnx = frag rot2c+1
    int hnx = ((rot2c + 1) & 31) * 32;
    Hh[0]  = *(const v8h*)&hHs[hbase + rot2c * 32];
    Hl_[0] = *(const v8h*)&hLs[hbase + rot2c * 32];

    int vo2 = tid16 + ((rot2c + 3) & 31) * 16384;   // next refill = chunk +3

    v4f c0H = v4f{b2r0, b2r0, b2r0, b2r0}, c0M = v4f{0.f, 0.f, 0.f, 0.f};
    v4f c1H = v4f{b2r1, b2r1, b2r1, b2r1}, c1M = v4f{0.f, 0.f, 0.f, 0.f};

    // ======== GEMM2: rotated chunk walk; bodies 0..23 uniform, tail peeled ==
    #pragma unroll 1
    for (int jj = 0; jj < 4; ++jj) {
      const int jb = jj * 6;
      G2BODY(jb + 0, 0, 0, 1, 1, 8);
      G2BODY(jb + 1, 1, 1, 1, 1, 8);
      G2BODY(jb + 2, 2, 0, 1, 1, 8);
      G2BODY(jb + 3, 0, 1, 1, 1, 8);
      G2BODY(jb + 4, 1, 0, 1, 1, 8);
      G2BODY(jb + 5, 2, 1, 1, 1, 8);
    }
    G2BODY(24, 0, 0, 1, 1, 8);
    G2BODY(25, 1, 1, 1, 1, 8);
    G2BODY(26, 2, 0, 1, 1, 8);
    G2BODY(27, 0, 1, 1, 1, 8);
    G2BODY(28, 1, 0, 1, 1, 8);
    G2BODY(29, 2, 1, 0, 1, 8);
    G2BODY(30, 0, 0, 0, 1, 4);
    G2BODY(31, 1, 1, 0, 0, 0);

    // ---- y epilogue + out stores
    #pragma unroll
    for (int j = 0; j < 4; ++j) {
      int m = g * 4 + j;
      float yn0 = ya[j] + dt * (c0H[j] + c0M[j] * (1.f / 2048.f));
      ya[j] = yn0;
      out[((size_t)((b0 + m) * 256 + nloc)) * 64 + (t + 1)] = yn0;
      float yn1 = yb[j] + dt * (c1H[j] + c1M[j] * (1.f / 2048.f));
      yb[j] = yn1;
      out[((size_t)((b0 + m) * 256 + 128 + nloc)) * 64 + (t + 1)] = yn1;
    }
    // ---- next step's G1 prologue (sites rot8*10..+4)
    if (t < 62) {
      #pragma unroll
      for (int s = 0; s < 5; ++s) {
        GLOAD(B1H[s], w1hB, g1p0 + s * 8192);
        GLOAD(B1L[s], w1lB, g1p0 + s * 8192);
      }
    }
  }
}

extern "C" void kernel_launch(void* const* d_in, const int* in_sizes, int n_in,
                              void* d_out, int out_size, void* d_ws, size_t ws_size,
                              hipStream_t stream) {
  const float* actions = (const float*)d_in[1];
  const float* y0      = (const float*)d_in[2];
  const float* W1      = (const float*)d_in[3];
  const float* b1      = (const float*)d_in[4];
  const float* W2      = (const float*)d_in[5];
  const float* b2      = (const float*)d_in[6];
  const float* dtp     = (const float*)d_in[7];
  float* out = (float*)d_out;
  _Float16* ws = (_Float16*)d_ws;

  const bool use_att = ws_size >= ATT_BYTES_NEEDED;
  float* att = use_att ? (float*)((char*)d_ws + 2359296) : nullptr;

  hipLaunchKernelGGL(conv_w, dim3(3584), dim3(256), 0, stream, W1, W2, ws);
  if (use_att)
    hipLaunchKernelGGL(conv_a, dim3(65536), dim3(256), 0, stream, actions, att);
  hipLaunchKernelGGL(ode_kernel, dim3(256), dim3(NT), 0, stream,
                     actions, att, y0, b1, b2, dtp, ws, out);
}